// Round 3
// baseline (366.172 us; speedup 1.0000x reference)
//
#include <hip/hip_runtime.h>
#include <cstdint>
#include <cstddef>

// COINBlock (RetNet-style retention, parallel form) on MI355X.
// Shapes: B=2, T=4096, I=C=1024.
//   Q = X@Wq, K = X@Wk, V = X@Wv            (bf16 MFMA, fp32 accum)
//   P = (Q K^T) * D,  D[n,m] = g^(n-m)*[n>=m]   (lower-tri tiles only)
//   out^T[i][t] = sum_m V^T[i][m] * P[t][m]     (output IS the transposed layout)
//   S_n passthrough (zeros) -> memset.
// All GEMMs are gemm_bt form: C[m][n] = sum_k A[m][k]*B[n][k], A/B row-major k-contiguous.
// R2: global_load_lds width-16 staging (m97 lever).
// R3: k_pv split-K (1280 blocks of <=32 ksteps, big-first) + fp32 HW atomics into
//     pre-zeroed out. Fixes occupancy=12% (512-block grid had <=2 blocks/CU resident).

using bf16x8 = __attribute__((ext_vector_type(8))) short;
using s16x4  = __attribute__((ext_vector_type(4))) short;
using f32x4  = __attribute__((ext_vector_type(4))) float;

#define TM 128
#define BK 32
#define T_SEQ 4096
#define C_DIM 1024

static constexpr float L2G = -0.0144995697f; // log2(0.99)

__device__ __forceinline__ short f2bf(float f) {
  unsigned u = __builtin_bit_cast(unsigned, f);
  u += 0x7FFFu + ((u >> 16) & 1u);   // round-to-nearest-even
  return (short)(u >> 16);
}

// async 16B/lane global->LDS. LDS dest semantics: wave-uniform base + lane*16,
// so the passed per-lane pointer must equal base + lane*16 (ours does).
__device__ __forceinline__ void async_ld16(const short* g, const short* l) {
  __builtin_amdgcn_global_load_lds(
      (const __attribute__((address_space(1))) unsigned int*)(uintptr_t)g,
      (__attribute__((address_space(3))) unsigned int*)(unsigned)(uintptr_t)l,
      16, 0, 0);
}

// K-loop core: 128x128 tile, 4 waves in 2x2, each wave 4x4 of 16x16x32 MFMA.
// A,B point at tile origin; k advances by BK per step.
__device__ __forceinline__ void gemm_bt_core(
    const short* __restrict__ A, const short* __restrict__ B,
    int ldk, int ksteps, short* lsA, short* lsB, f32x4 acc[4][4])
{
  const int tid  = threadIdx.x;
  const int lane = tid & 63;
  const int wave = tid >> 6;
  const int wr   = (wave >> 1) * 64;
  const int wc   = (wave & 1) * 64;
  const int quad = lane >> 4;
  const int l15  = lane & 15;
  const int srow = lane >> 2;        // 0..15 within chunk
  const int sko  = (lane & 3) * 8;   // bf16 offset within row

  for (int ks = 0; ks < ksteps; ++ks) {
    __syncthreads();   // prev iter's frag reads done before LDS overwrite
#pragma unroll
    for (int j = 0; j < 2; ++j) {
      const int c   = wave * 2 + j;      // 8 chunks of 16 rows per 8KB tile
      const int row = c * 16 + srow;
      async_ld16(A + (size_t)row * ldk + sko, lsA + c * 512 + lane * 8);
      async_ld16(B + (size_t)row * ldk + sko, lsB + c * 512 + lane * 8);
    }
    __syncthreads();   // drains vmcnt -> staged data visible

    bf16x8 af[4], bf[4];
#pragma unroll
    for (int i = 0; i < 4; ++i)
      af[i] = *(const bf16x8*)&lsA[(wr + i * 16 + l15) * BK + quad * 8];
#pragma unroll
    for (int i = 0; i < 4; ++i)
      bf[i] = *(const bf16x8*)&lsB[(wc + i * 16 + l15) * BK + quad * 8];

#pragma unroll
    for (int mi = 0; mi < 4; ++mi)
#pragma unroll
      for (int ni = 0; ni < 4; ++ni)
        acc[mi][ni] = __builtin_amdgcn_mfma_f32_16x16x32_bf16(
            af[mi], bf[ni], acc[mi][ni], 0, 0, 0);

    A += BK; B += BK;
  }
}

// ---------------- converts ----------------

__global__ __launch_bounds__(256) void k_convX(const float* __restrict__ x,
                                               short* __restrict__ y) {
  const size_t i = ((size_t)blockIdx.x * 256 + threadIdx.x) * 4;
  const float4 v = *(const float4*)(x + i);
  s16x4 o;
  o[0] = f2bf(v.x); o[1] = f2bf(v.y); o[2] = f2bf(v.z); o[3] = f2bf(v.w);
  *(s16x4*)(y + i) = o;
}

// transpose 1024x1024 W[i][c] -> bf16 Wt[c][i], 32x32 LDS tiles
__global__ __launch_bounds__(256) void k_convWt(const float* __restrict__ Wq,
                                                const float* __restrict__ Wk,
                                                const float* __restrict__ Wv,
                                                short* __restrict__ Wtq,
                                                short* __restrict__ Wtk,
                                                short* __restrict__ Wtv) {
  const float* W = (blockIdx.z == 0) ? Wq : (blockIdx.z == 1) ? Wk : Wv;
  short* Wt      = (blockIdx.z == 0) ? Wtq : (blockIdx.z == 1) ? Wtk : Wtv;
  __shared__ float t[32][33];
  const int tx = threadIdx.x & 31;
  const int ty = threadIdx.x >> 5;           // 0..7
  const int bc = blockIdx.x * 32;            // c tile
  const int bi = blockIdx.y * 32;            // i tile
#pragma unroll
  for (int j = 0; j < 32; j += 8)
    t[ty + j][tx] = W[(size_t)(bi + ty + j) * 1024 + bc + tx];
  __syncthreads();
#pragma unroll
  for (int j = 0; j < 32; j += 8)
    Wt[(size_t)(bc + ty + j) * 1024 + bi + tx] = f2bf(t[tx][ty + j]);
}

// ---------------- GEMMs ----------------

// Q/K projection: A = Xb [8192 x 1024], B = Wt [1024(c) x 1024(k)], out bf16 [8192 x 1024]
__global__ __launch_bounds__(256) void k_proj_qk(const short* __restrict__ Xb,
                                                 const short* __restrict__ Wtq,
                                                 const short* __restrict__ Wtk,
                                                 short* __restrict__ Qb,
                                                 short* __restrict__ Kb) {
  __shared__ short lsA[TM * BK];
  __shared__ short lsB[TM * BK];
  f32x4 acc[4][4];
#pragma unroll
  for (int i = 0; i < 4; ++i)
#pragma unroll
    for (int j = 0; j < 4; ++j) acc[i][j] = 0.f;

  const short* W = blockIdx.z ? Wtk : Wtq;
  short* O       = blockIdx.z ? Kb : Qb;
  const short* A = Xb + (size_t)blockIdx.y * 128 * 1024;
  const short* B = W  + (size_t)blockIdx.x * 128 * 1024;
  gemm_bt_core(A, B, 1024, 32, lsA, lsB, acc);

  const int lane = threadIdx.x & 63, wave = threadIdx.x >> 6;
  const int wr = (wave >> 1) * 64, wc = (wave & 1) * 64;
  const int quad = lane >> 4, l15 = lane & 15;
#pragma unroll
  for (int mi = 0; mi < 4; ++mi)
#pragma unroll
    for (int ni = 0; ni < 4; ++ni)
#pragma unroll
      for (int r = 0; r < 4; ++r) {
        const int rl = wr + mi * 16 + quad * 4 + r;
        const int cl = wc + ni * 16 + l15;
        O[(size_t)(blockIdx.y * 128 + rl) * 1024 + blockIdx.x * 128 + cl] =
            f2bf(acc[mi][ni][r]);
      }
}

// V^T projection: A = Wt_v [1024(i) x 1024(k)], B = Xb_batch [4096(t) x 1024(k)],
// out Vt[b][i][t] bf16
__global__ __launch_bounds__(256) void k_proj_v(const short* __restrict__ Wtv,
                                                const short* __restrict__ Xb,
                                                short* __restrict__ Vt) {
  __shared__ short lsA[TM * BK];
  __shared__ short lsB[TM * BK];
  f32x4 acc[4][4];
#pragma unroll
  for (int i = 0; i < 4; ++i)
#pragma unroll
    for (int j = 0; j < 4; ++j) acc[i][j] = 0.f;

  const size_t b = blockIdx.z;
  const short* A = Wtv + (size_t)blockIdx.y * 128 * 1024;
  const short* B = Xb + b * T_SEQ * C_DIM + (size_t)blockIdx.x * 128 * 1024;
  gemm_bt_core(A, B, 1024, 32, lsA, lsB, acc);

  short* O = Vt + b * C_DIM * T_SEQ;
  const int lane = threadIdx.x & 63, wave = threadIdx.x >> 6;
  const int wr = (wave >> 1) * 64, wc = (wave & 1) * 64;
  const int quad = lane >> 4, l15 = lane & 15;
#pragma unroll
  for (int mi = 0; mi < 4; ++mi)
#pragma unroll
    for (int ni = 0; ni < 4; ++ni)
#pragma unroll
      for (int r = 0; r < 4; ++r) {
        const int rl = wr + mi * 16 + quad * 4 + r;   // i local
        const int cl = wc + ni * 16 + l15;            // t local
        O[(size_t)(blockIdx.y * 128 + rl) * T_SEQ + blockIdx.x * 128 + cl] =
            f2bf(acc[mi][ni][r]);
      }
}

// Scores: P[b][n][m] = bf16( (Q_n . K_m) * g^(n-m) * [n>=m] ). Lower-tri tiles only.
__global__ __launch_bounds__(256) void k_scores(const short* __restrict__ Qb,
                                                const short* __restrict__ Kb,
                                                short* __restrict__ P) {
  if (blockIdx.y < blockIdx.x) return;   // pure upper-triangle tile: never read
  __shared__ short lsA[TM * BK];
  __shared__ short lsB[TM * BK];
  f32x4 acc[4][4];
#pragma unroll
  for (int i = 0; i < 4; ++i)
#pragma unroll
    for (int j = 0; j < 4; ++j) acc[i][j] = 0.f;

  const size_t b = blockIdx.z;
  const short* A = Qb + b * T_SEQ * C_DIM + (size_t)blockIdx.y * 128 * 1024;
  const short* B = Kb + b * T_SEQ * C_DIM + (size_t)blockIdx.x * 128 * 1024;
  gemm_bt_core(A, B, 1024, 32, lsA, lsB, acc);

  short* Pb = P + b * (size_t)T_SEQ * T_SEQ;
  const int lane = threadIdx.x & 63, wave = threadIdx.x >> 6;
  const int wr = (wave >> 1) * 64, wc = (wave & 1) * 64;
  const int quad = lane >> 4, l15 = lane & 15;
#pragma unroll
  for (int mi = 0; mi < 4; ++mi)
#pragma unroll
    for (int ni = 0; ni < 4; ++ni)
#pragma unroll
      for (int r = 0; r < 4; ++r) {
        const int n = blockIdx.y * 128 + wr + mi * 16 + quad * 4 + r;
        const int m = blockIdx.x * 128 + wc + ni * 16 + l15;
        float v = 0.f;
        if (n >= m) v = acc[mi][ni][r] * exp2f((float)(n - m) * L2G);
        Pb[(size_t)n * T_SEQ + m] = f2bf(v);
      }
}

// PV split-K: out[b][i][t] += sum over one K-chunk of Vt[b][i][m] * P[b][t][m].
// Grid.x = 80 chunks covering t-tiles x=0..31 with ceil((x+1)/8) chunks of <=32
// ksteps each, enumerated BIG-FIRST (x descending) to minimize dispatch tail.
// Partials accumulate via HW fp32 atomics into pre-zeroed out.
__global__ __launch_bounds__(256) void k_pv(const short* __restrict__ Vt,
                                            const short* __restrict__ P,
                                            float* __restrict__ out) {
  __shared__ short lsA[TM * BK];
  __shared__ short lsB[TM * BK];
  f32x4 acc[4][4];
#pragma unroll
  for (int i = 0; i < 4; ++i)
#pragma unroll
    for (int j = 0; j < 4; ++j) acc[i][j] = 0.f;

  // map blockIdx.x in [0,80) -> (xt, chunk), xt descending
  int cx = blockIdx.x;
  int xt = 0, ch = 0;
  for (int x = 31; x >= 0; --x) {
    const int n = (x + 8) >> 3;          // ceil((x+1)/8)
    if (cx < n) { xt = x; ch = cx; break; }
    cx -= n;
  }
  const int k0 = ch * 32;                            // kstep offset
  const int ks = min((xt + 1) * 4 - k0, 32);         // ksteps this block

  const size_t b = blockIdx.z;
  const short* A = Vt + b * C_DIM * T_SEQ + (size_t)blockIdx.y * 128 * T_SEQ
                      + (size_t)k0 * BK;
  const short* B = P + b * (size_t)T_SEQ * T_SEQ + (size_t)xt * 128 * T_SEQ
                     + (size_t)k0 * BK;
  gemm_bt_core(A, B, T_SEQ, ks, lsA, lsB, acc);

  float* Ob = out + b * (size_t)C_DIM * T_SEQ;
  const int lane = threadIdx.x & 63, wave = threadIdx.x >> 6;
  const int wr = (wave >> 1) * 64, wc = (wave & 1) * 64;
  const int quad = lane >> 4, l15 = lane & 15;
#pragma unroll
  for (int mi = 0; mi < 4; ++mi)
#pragma unroll
    for (int ni = 0; ni < 4; ++ni)
#pragma unroll
      for (int r = 0; r < 4; ++r) {
        const int rl = blockIdx.y * 128 + wr + mi * 16 + quad * 4 + r;  // i
        const int cl = xt * 128 + wc + ni * 16 + l15;                   // t
        unsafeAtomicAdd(&Ob[(size_t)rl * T_SEQ + cl], acc[mi][ni][r]);
      }
}

// ---------------- launch ----------------

extern "C" void kernel_launch(void* const* d_in, const int* in_sizes, int n_in,
                              void* d_out, int out_size, void* d_ws, size_t ws_size,
                              hipStream_t stream) {
  const float* X  = (const float*)d_in[0];
  // d_in[1] att_mask (unused), d_in[2] S_n (zeros, passthrough)
  const float* Wq = (const float*)d_in[3];
  const float* Wk = (const float*)d_in[4];
  const float* Wv = (const float*)d_in[5];
  float* out = (float*)d_out;

  // workspace layout (bytes); total 140,509,184 (~134 MiB)
  char* ws = (char*)d_ws;
  short* Xb  = (short*)(ws);                 // 16,777,216  X bf16 [B*T, I]
  short* Wtq = (short*)(ws + 16777216);      //  2,097,152  Wq^T bf16 [c][i]
  short* Wtk = (short*)(ws + 18874368);      //  2,097,152
  short* Wtv = (short*)(ws + 20971520);      //  2,097,152
  short* Qb  = (short*)(ws + 23068672);      // 16,777,216  [B*T, C]
  short* Kb  = (short*)(ws + 39845888);      // 16,777,216
  short* Vt  = (short*)(ws + 56623104);      // 16,777,216  [B, I, T]
  short* P   = (short*)(ws + 73400320);      // 67,108,864  [B, T, T]

  // zero entire output (PV atomically accumulates; S_n passthrough stays 0)
  hipMemsetAsync(out, 0, (size_t)out_size * sizeof(float), stream);

  k_convX  <<<dim3(8192),       dim3(256), 0, stream>>>(X, Xb);
  k_convWt <<<dim3(32, 32, 3),  dim3(256), 0, stream>>>(Wq, Wk, Wv, Wtq, Wtk, Wtv);
  k_proj_qk<<<dim3(8, 64, 2),   dim3(256), 0, stream>>>(Xb, Wtq, Wtk, Qb, Kb);
  k_proj_v <<<dim3(32, 8, 2),   dim3(256), 0, stream>>>(Wtv, Xb, Vt);
  k_scores <<<dim3(32, 32, 2),  dim3(256), 0, stream>>>(Qb, Kb, P);
  k_pv     <<<dim3(80, 8, 2),   dim3(256), 0, stream>>>(Vt, P, out);
}

// Round 4
// 348.151 us; speedup vs baseline: 1.0518x; 1.0518x over previous
//
#include <hip/hip_runtime.h>
#include <cstdint>
#include <cstddef>

// COINBlock (RetNet-style retention, parallel form) on MI355X.
// Shapes: B=2, T=4096, I=C=1024.
//   Q = X@Wq, K = X@Wk, V = X@Wv            (bf16 MFMA, fp32 accum)
//   P = (Q K^T) * D,  D[n,m] = g^(n-m)*[n>=m]   (lower-tri tiles only)
//   out^T[i][t] = sum_m V^T[i][m] * P[t][m]     (output IS the transposed layout)
//   S_n passthrough (zeros) -> memset.
// All GEMMs are gemm_bt form: C[m][n] = sum_k A[m][k]*B[n][k], A/B row-major k-contiguous.
// R2: global_load_lds width-16 staging (m97 lever).
// R3: k_pv split-K + fp32 HW atomics into pre-zeroed out.
// R4: K-loop restructure: LDS double-buffer with SINGLE barrier/kstep (prefetch
//     distance = one full iteration, so the vmcnt(0)-at-barrier drains loads issued
//     ~one iteration earlier) + XOR chunk swizzle on global addresses to kill the
//     4-8 way ds_read_b128 bank conflicts (2-way is free).

using bf16x8 = __attribute__((ext_vector_type(8))) short;
using s16x4  = __attribute__((ext_vector_type(4))) short;
using f32x4  = __attribute__((ext_vector_type(4))) float;

#define TM 128
#define BK 32
#define TILE_SH 4096   // shorts per 128x32 tile (8 KB)
#define T_SEQ 4096
#define C_DIM 1024

static constexpr float L2G = -0.0144995697f; // log2(0.99)

__device__ __forceinline__ short f2bf(float f) {
  unsigned u = __builtin_bit_cast(unsigned, f);
  u += 0x7FFFu + ((u >> 16) & 1u);   // round-to-nearest-even
  return (short)(u >> 16);
}

// async 16B/lane global->LDS. LDS dest semantics: wave-uniform base + lane*16.
__device__ __forceinline__ void async_ld16(const short* g, const short* l) {
  __builtin_amdgcn_global_load_lds(
      (const __attribute__((address_space(1))) unsigned int*)(uintptr_t)g,
      (__attribute__((address_space(3))) unsigned int*)(unsigned)(uintptr_t)l,
      16, 0, 0);
}

// Stage one 128x32 A-tile + B-tile into LDS buffer `buf`.
// Swizzle: LDS slot s of row r holds global 16B-chunk s ^ ((r>>1)&3); readers
// invert. For the writer, (row>>1)&3 == (lane>>3)&3 (row = c*16 + lane/4).
__device__ __forceinline__ void stage_tiles(const short* __restrict__ A,
                                            const short* __restrict__ B,
                                            short* lsA, short* lsB, int buf,
                                            int wave, int lane, int ldk) {
  const int srow = lane >> 2;                              // row within 16-row chunk
  const int cg   = ((lane & 3) ^ ((lane >> 3) & 3)) * 8;   // swizzled global chunk (shorts)
#pragma unroll
  for (int j = 0; j < 2; ++j) {
    const int c   = wave * 2 + j;        // 8 chunks of 16 rows per tile
    const int row = c * 16 + srow;
    async_ld16(A + (size_t)row * ldk + cg, lsA + buf * TILE_SH + c * 512 + lane * 8);
    async_ld16(B + (size_t)row * ldk + cg, lsB + buf * TILE_SH + c * 512 + lane * 8);
  }
}

// K-loop core: 128x128 tile, 4 waves in 2x2, each wave 4x4 of 16x16x32 MFMA.
// Double-buffered LDS, one barrier per kstep.
__device__ __forceinline__ void gemm_bt_core(
    const short* __restrict__ A, const short* __restrict__ B,
    int ldk, int ksteps, short* lsA, short* lsB, f32x4 acc[4][4])
{
  const int tid  = threadIdx.x;
  const int lane = tid & 63;
  const int wave = tid >> 6;
  const int wr   = (wave >> 1) * 64;
  const int wc   = (wave & 1) * 64;
  const int quad = lane >> 4;
  const int l15  = lane & 15;
  const int sw   = (l15 >> 1) & 3;    // read-side swizzle: slot = quad ^ sw

  stage_tiles(A, B, lsA, lsB, 0, wave, lane, ldk);   // prologue prefetch

  for (int ks = 0; ks < ksteps; ++ks) {
    const int buf = ks & 1;
    __syncthreads();   // drains vmcnt -> buf's tiles (issued last iter) ready;
                       // also: everyone done reading buf^1 from iter ks-1
    if (ks + 1 < ksteps)
      stage_tiles(A + (size_t)(ks + 1) * BK, B + (size_t)(ks + 1) * BK,
                  lsA, lsB, buf ^ 1, wave, lane, ldk);

    bf16x8 af[4], bf[4];
#pragma unroll
    for (int i = 0; i < 4; ++i)
      af[i] = *(const bf16x8*)&lsA[buf * TILE_SH + (wr + i * 16 + l15) * BK + (quad ^ sw) * 8];
#pragma unroll
    for (int i = 0; i < 4; ++i)
      bf[i] = *(const bf16x8*)&lsB[buf * TILE_SH + (wc + i * 16 + l15) * BK + (quad ^ sw) * 8];

#pragma unroll
    for (int mi = 0; mi < 4; ++mi)
#pragma unroll
      for (int ni = 0; ni < 4; ++ni)
        acc[mi][ni] = __builtin_amdgcn_mfma_f32_16x16x32_bf16(
            af[mi], bf[ni], acc[mi][ni], 0, 0, 0);
  }
}

// ---------------- converts ----------------

__global__ __launch_bounds__(256) void k_convX(const float* __restrict__ x,
                                               short* __restrict__ y) {
  const size_t i = ((size_t)blockIdx.x * 256 + threadIdx.x) * 4;
  const float4 v = *(const float4*)(x + i);
  s16x4 o;
  o[0] = f2bf(v.x); o[1] = f2bf(v.y); o[2] = f2bf(v.z); o[3] = f2bf(v.w);
  *(s16x4*)(y + i) = o;
}

// transpose 1024x1024 W[i][c] -> bf16 Wt[c][i], 32x32 LDS tiles
__global__ __launch_bounds__(256) void k_convWt(const float* __restrict__ Wq,
                                                const float* __restrict__ Wk,
                                                const float* __restrict__ Wv,
                                                short* __restrict__ Wtq,
                                                short* __restrict__ Wtk,
                                                short* __restrict__ Wtv) {
  const float* W = (blockIdx.z == 0) ? Wq : (blockIdx.z == 1) ? Wk : Wv;
  short* Wt      = (blockIdx.z == 0) ? Wtq : (blockIdx.z == 1) ? Wtk : Wtv;
  __shared__ float t[32][33];
  const int tx = threadIdx.x & 31;
  const int ty = threadIdx.x >> 5;           // 0..7
  const int bc = blockIdx.x * 32;            // c tile
  const int bi = blockIdx.y * 32;            // i tile
#pragma unroll
  for (int j = 0; j < 32; j += 8)
    t[ty + j][tx] = W[(size_t)(bi + ty + j) * 1024 + bc + tx];
  __syncthreads();
#pragma unroll
  for (int j = 0; j < 32; j += 8)
    Wt[(size_t)(bc + ty + j) * 1024 + bi + tx] = f2bf(t[tx][ty + j]);
}

// ---------------- GEMMs ----------------

// Q/K projection: A = Xb [8192 x 1024], B = Wt [1024(c) x 1024(k)], out bf16 [8192 x 1024]
__global__ __launch_bounds__(256) void k_proj_qk(const short* __restrict__ Xb,
                                                 const short* __restrict__ Wtq,
                                                 const short* __restrict__ Wtk,
                                                 short* __restrict__ Qb,
                                                 short* __restrict__ Kb) {
  __shared__ short lsA[2 * TILE_SH];
  __shared__ short lsB[2 * TILE_SH];
  f32x4 acc[4][4];
#pragma unroll
  for (int i = 0; i < 4; ++i)
#pragma unroll
    for (int j = 0; j < 4; ++j) acc[i][j] = 0.f;

  const short* W = blockIdx.z ? Wtk : Wtq;
  short* O       = blockIdx.z ? Kb : Qb;
  const short* A = Xb + (size_t)blockIdx.y * 128 * 1024;
  const short* B = W  + (size_t)blockIdx.x * 128 * 1024;
  gemm_bt_core(A, B, 1024, 32, lsA, lsB, acc);

  const int lane = threadIdx.x & 63, wave = threadIdx.x >> 6;
  const int wr = (wave >> 1) * 64, wc = (wave & 1) * 64;
  const int quad = lane >> 4, l15 = lane & 15;
#pragma unroll
  for (int mi = 0; mi < 4; ++mi)
#pragma unroll
    for (int ni = 0; ni < 4; ++ni)
#pragma unroll
      for (int r = 0; r < 4; ++r) {
        const int rl = wr + mi * 16 + quad * 4 + r;
        const int cl = wc + ni * 16 + l15;
        O[(size_t)(blockIdx.y * 128 + rl) * 1024 + blockIdx.x * 128 + cl] =
            f2bf(acc[mi][ni][r]);
      }
}

// V^T projection: A = Wt_v [1024(i) x 1024(k)], B = Xb_batch [4096(t) x 1024(k)],
// out Vt[b][i][t] bf16
__global__ __launch_bounds__(256) void k_proj_v(const short* __restrict__ Wtv,
                                                const short* __restrict__ Xb,
                                                short* __restrict__ Vt) {
  __shared__ short lsA[2 * TILE_SH];
  __shared__ short lsB[2 * TILE_SH];
  f32x4 acc[4][4];
#pragma unroll
  for (int i = 0; i < 4; ++i)
#pragma unroll
    for (int j = 0; j < 4; ++j) acc[i][j] = 0.f;

  const size_t b = blockIdx.z;
  const short* A = Wtv + (size_t)blockIdx.y * 128 * 1024;
  const short* B = Xb + b * T_SEQ * C_DIM + (size_t)blockIdx.x * 128 * 1024;
  gemm_bt_core(A, B, 1024, 32, lsA, lsB, acc);

  short* O = Vt + b * C_DIM * T_SEQ;
  const int lane = threadIdx.x & 63, wave = threadIdx.x >> 6;
  const int wr = (wave >> 1) * 64, wc = (wave & 1) * 64;
  const int quad = lane >> 4, l15 = lane & 15;
#pragma unroll
  for (int mi = 0; mi < 4; ++mi)
#pragma unroll
    for (int ni = 0; ni < 4; ++ni)
#pragma unroll
      for (int r = 0; r < 4; ++r) {
        const int rl = wr + mi * 16 + quad * 4 + r;   // i local
        const int cl = wc + ni * 16 + l15;            // t local
        O[(size_t)(blockIdx.y * 128 + rl) * T_SEQ + blockIdx.x * 128 + cl] =
            f2bf(acc[mi][ni][r]);
      }
}

// Scores: P[b][n][m] = bf16( (Q_n . K_m) * g^(n-m) * [n>=m] ). Lower-tri tiles only.
__global__ __launch_bounds__(256) void k_scores(const short* __restrict__ Qb,
                                                const short* __restrict__ Kb,
                                                short* __restrict__ P) {
  if (blockIdx.y < blockIdx.x) return;   // pure upper-triangle tile: never read
  __shared__ short lsA[2 * TILE_SH];
  __shared__ short lsB[2 * TILE_SH];
  f32x4 acc[4][4];
#pragma unroll
  for (int i = 0; i < 4; ++i)
#pragma unroll
    for (int j = 0; j < 4; ++j) acc[i][j] = 0.f;

  const size_t b = blockIdx.z;
  const short* A = Qb + b * T_SEQ * C_DIM + (size_t)blockIdx.y * 128 * 1024;
  const short* B = Kb + b * T_SEQ * C_DIM + (size_t)blockIdx.x * 128 * 1024;
  gemm_bt_core(A, B, 1024, 32, lsA, lsB, acc);

  short* Pb = P + b * (size_t)T_SEQ * T_SEQ;
  const int lane = threadIdx.x & 63, wave = threadIdx.x >> 6;
  const int wr = (wave >> 1) * 64, wc = (wave & 1) * 64;
  const int quad = lane >> 4, l15 = lane & 15;
#pragma unroll
  for (int mi = 0; mi < 4; ++mi)
#pragma unroll
    for (int ni = 0; ni < 4; ++ni)
#pragma unroll
      for (int r = 0; r < 4; ++r) {
        const int n = blockIdx.y * 128 + wr + mi * 16 + quad * 4 + r;
        const int m = blockIdx.x * 128 + wc + ni * 16 + l15;
        float v = 0.f;
        if (n >= m) v = acc[mi][ni][r] * exp2f((float)(n - m) * L2G);
        Pb[(size_t)n * T_SEQ + m] = f2bf(v);
      }
}

// PV split-K: out[b][i][t] += sum over one K-chunk of Vt[b][i][m] * P[b][t][m].
// Grid.x = 80 chunks covering t-tiles x=0..31 with ceil((x+1)/8) chunks of <=32
// ksteps each, enumerated BIG-FIRST (x descending). HW fp32 atomics into
// pre-zeroed out.
__global__ __launch_bounds__(256) void k_pv(const short* __restrict__ Vt,
                                            const short* __restrict__ P,
                                            float* __restrict__ out) {
  __shared__ short lsA[2 * TILE_SH];
  __shared__ short lsB[2 * TILE_SH];
  f32x4 acc[4][4];
#pragma unroll
  for (int i = 0; i < 4; ++i)
#pragma unroll
    for (int j = 0; j < 4; ++j) acc[i][j] = 0.f;

  // map blockIdx.x in [0,80) -> (xt, chunk), xt descending
  int cx = blockIdx.x;
  int xt = 0, ch = 0;
  for (int x = 31; x >= 0; --x) {
    const int n = (x + 8) >> 3;          // ceil((x+1)/8)
    if (cx < n) { xt = x; ch = cx; break; }
    cx -= n;
  }
  const int k0 = ch * 32;                            // kstep offset
  const int ks = min((xt + 1) * 4 - k0, 32);         // ksteps this block

  const size_t b = blockIdx.z;
  const short* A = Vt + b * C_DIM * T_SEQ + (size_t)blockIdx.y * 128 * T_SEQ
                      + (size_t)k0 * BK;
  const short* B = P + b * (size_t)T_SEQ * T_SEQ + (size_t)xt * 128 * T_SEQ
                     + (size_t)k0 * BK;
  gemm_bt_core(A, B, T_SEQ, ks, lsA, lsB, acc);

  float* Ob = out + b * (size_t)C_DIM * T_SEQ;
  const int lane = threadIdx.x & 63, wave = threadIdx.x >> 6;
  const int wr = (wave >> 1) * 64, wc = (wave & 1) * 64;
  const int quad = lane >> 4, l15 = lane & 15;
#pragma unroll
  for (int mi = 0; mi < 4; ++mi)
#pragma unroll
    for (int ni = 0; ni < 4; ++ni)
#pragma unroll
      for (int r = 0; r < 4; ++r) {
        const int rl = blockIdx.y * 128 + wr + mi * 16 + quad * 4 + r;  // i
        const int cl = xt * 128 + wc + ni * 16 + l15;                   // t
        unsafeAtomicAdd(&Ob[(size_t)rl * T_SEQ + cl], acc[mi][ni][r]);
      }
}

// ---------------- launch ----------------

extern "C" void kernel_launch(void* const* d_in, const int* in_sizes, int n_in,
                              void* d_out, int out_size, void* d_ws, size_t ws_size,
                              hipStream_t stream) {
  const float* X  = (const float*)d_in[0];
  // d_in[1] att_mask (unused), d_in[2] S_n (zeros, passthrough)
  const float* Wq = (const float*)d_in[3];
  const float* Wk = (const float*)d_in[4];
  const float* Wv = (const float*)d_in[5];
  float* out = (float*)d_out;

  // workspace layout (bytes); total 140,509,184 (~134 MiB)
  char* ws = (char*)d_ws;
  short* Xb  = (short*)(ws);                 // 16,777,216  X bf16 [B*T, I]
  short* Wtq = (short*)(ws + 16777216);      //  2,097,152  Wq^T bf16 [c][i]
  short* Wtk = (short*)(ws + 18874368);      //  2,097,152
  short* Wtv = (short*)(ws + 20971520);      //  2,097,152
  short* Qb  = (short*)(ws + 23068672);      // 16,777,216  [B*T, C]
  short* Kb  = (short*)(ws + 39845888);      // 16,777,216
  short* Vt  = (short*)(ws + 56623104);      // 16,777,216  [B, I, T]
  short* P   = (short*)(ws + 73400320);      // 67,108,864  [B, T, T]

  // zero entire output (PV atomically accumulates; S_n passthrough stays 0)
  hipMemsetAsync(out, 0, (size_t)out_size * sizeof(float), stream);

  k_convX  <<<dim3(8192),       dim3(256), 0, stream>>>(X, Xb);
  k_convWt <<<dim3(32, 32, 3),  dim3(256), 0, stream>>>(Wq, Wk, Wv, Wtq, Wtk, Wtv);
  k_proj_qk<<<dim3(8, 64, 2),   dim3(256), 0, stream>>>(Xb, Wtq, Wtk, Qb, Kb);
  k_proj_v <<<dim3(32, 8, 2),   dim3(256), 0, stream>>>(Wtv, Xb, Vt);
  k_scores <<<dim3(32, 32, 2),  dim3(256), 0, stream>>>(Qb, Kb, P);
  k_pv     <<<dim3(80, 8, 2),   dim3(256), 0, stream>>>(Vt, P, out);
}